// Round 8
// baseline (162.554 us; speedup 1.0000x reference)
//
#include <hip/hip_runtime.h>
#include <math.h>

#define D128 128
#define SCAPW 256   // per-wave LDS score capacity (deg ~ Poisson(32); P(deg>256)~0)

typedef unsigned int uint32;
typedef unsigned short ushort_t;
typedef short bf16x8 __attribute__((ext_vector_type(8)));
typedef float f32x4 __attribute__((ext_vector_type(4)));
typedef float f32x2 __attribute__((ext_vector_type(2)));

// fp32 -> bf16 (RNE)
__device__ __forceinline__ ushort_t bf16_of(float x) {
  uint32 u = __float_as_uint(x);
  return (ushort_t)((u + 0x7fffu + ((u >> 16) & 1u)) >> 16);
}
__device__ __forceinline__ uint32 pack_bf2(float x, float y) {
  uint32 bx = __float_as_uint(x);
  uint32 by = __float_as_uint(y);
  bx = (bx + 0x7fffu + ((bx >> 16) & 1u)) >> 16;
  by = (by + 0x7fffu + ((by >> 16) & 1u)) & 0xffff0000u;
  return bx | by;
}

// tanh(x) = 1 - 2/(1+exp(2x)); exp(2x) folded to one v_mul + v_exp (exp2)
__device__ __forceinline__ float fast_tanh(float x) {
  float e = __builtin_exp2f(x * 2.8853900817779268f);
  float r = __builtin_amdgcn_rcpf(1.0f + e);
  return fmaf(-2.0f, r, 1.0f);
}

// pack 4 fp32 -> 4 OCP e4m3 fp8 in one uint (HW RNE)
__device__ __forceinline__ uint32 pack_fp8x4(float a, float b, float c, float d) {
  int u = __builtin_amdgcn_cvt_pk_fp8_f32(a, b, 0, false);
  u = __builtin_amdgcn_cvt_pk_fp8_f32(c, d, u, true);
  return (uint32)u;
}

// pack 8 consecutive fp32 (two float4) -> bf16x8 (memory order)
__device__ __forceinline__ bf16x8 bf16x8_of(float4 a, float4 c) {
  union { uint4 u; bf16x8 h; } r;
  r.u.x = pack_bf2(a.x, a.y);
  r.u.y = pack_bf2(a.z, a.w);
  r.u.z = pack_bf2(c.x, c.y);
  r.u.w = pack_bf2(c.z, c.w);
  return r.h;
}

// direct global->LDS DMA, 16B per lane (wave-uniform LDS base + lane*16)
__device__ __forceinline__ void gload_lds16(const void* g, void* l) {
  __builtin_amdgcn_global_load_lds(
      (const __attribute__((address_space(1))) unsigned int*)g,
      (__attribute__((address_space(3))) unsigned int*)l, 16, 0, 0);
}

// 8-channel tanh-weighted partial score from one fp8 row segment
__device__ __forceinline__ float score8(uint2 us, f32x2 pd0, f32x2 pd1, f32x2 pd2,
                                        f32x2 pd3, float4 wA, float4 wB) {
  f32x2 a0 = __builtin_amdgcn_cvt_pk_f32_fp8(us.x, false);
  f32x2 a1 = __builtin_amdgcn_cvt_pk_f32_fp8(us.x, true);
  f32x2 a2 = __builtin_amdgcn_cvt_pk_f32_fp8(us.y, false);
  f32x2 a3 = __builtin_amdgcn_cvt_pk_f32_fp8(us.y, true);
  float sc;
  sc = fast_tanh(a0.x + pd0.x) * wA.x;
  sc = fmaf(fast_tanh(a0.y + pd0.y), wA.y, sc);
  sc = fmaf(fast_tanh(a1.x + pd1.x), wA.z, sc);
  sc = fmaf(fast_tanh(a1.y + pd1.y), wA.w, sc);
  sc = fmaf(fast_tanh(a2.x + pd2.x), wB.x, sc);
  sc = fmaf(fast_tanh(a2.y + pd2.y), wB.y, sc);
  sc = fmaf(fast_tanh(a3.x + pd3.x), wB.z, sc);
  sc = fmaf(fast_tanh(a3.y + pd3.y), wB.w, sc);
  return sc;
}

// ---------------------------------------------------------------------------
// prep_all: W fragments + segment offsets only.
// ---------------------------------------------------------------------------
__global__ __launch_bounds__(256) void prep_all(
    const float* __restrict__ W1, const float* __restrict__ Wo,
    const int* __restrict__ dst_idx,
    ushort_t* __restrict__ Wfrag, ushort_t* __restrict__ Wo_frag,
    int* __restrict__ off, int E, int N) {
  const int b = blockIdx.x;
  const int tid = threadIdx.x;
  if (b < 16) {
    // W1 fragments: t indexes [h][nt][kc][lane]; frag[j]=W1[k][n] (k=quad*8+j)
    int t = b * 256 + tid;   // 0..4095
    int lane = t & 63;
    int kc = (t >> 6) & 3;
    int nt = (t >> 8) & 7;
    int h = (t >> 11) & 1;
    int m = lane & 15;
    int quad = lane >> 4;
    int krow = h * D128 + kc * 32 + quad * 8;
    int ncol = nt * 16 + m;
    ushort_t fr[8];
#pragma unroll
    for (int j = 0; j < 8; j++) fr[j] = bf16_of(W1[(size_t)(krow + j) * D128 + ncol]);
    *(uint4*)(Wfrag + (size_t)t * 8) = *(const uint4*)fr;
  } else if (b < 32) {
    // Wo fragments: t indexes [nt][kc8][lane], kc8 0..7 (K=256)
    int t = (b - 16) * 256 + tid;   // 0..4095
    int lane = t & 63;
    int kc = (t >> 6) & 7;
    int nt = (t >> 9) & 7;
    int m = lane & 15;
    int quad = lane >> 4;
    int krow = kc * 32 + quad * 8;
    int ncol = nt * 16 + m;
    ushort_t fr[8];
#pragma unroll
    for (int j = 0; j < 8; j++) fr[j] = bf16_of(Wo[(size_t)(krow + j) * D128 + ncol]);
    *(uint4*)(Wo_frag + (size_t)t * 8) = *(const uint4*)fr;
  } else {
    int e = (b - 32) * 256 + tid;
    if (e >= E) return;
    int d = dst_idx[e];
    int dprev = (e == 0) ? -1 : dst_idx[e - 1];
    for (int v = dprev + 1; v <= d; v++) off[v] = e;
    if (e == E - 1) {
      for (int v = d + 1; v <= N; v++) off[v] = E;
    }
  }
}

// ---------------------------------------------------------------------------
// Merged GEMM, fp8 output. 64-row tiles; W half staged once/block into LDS
// via global_load_lds DMA (no VGPR round trip); LDS reused for the fp8
// repack epilogue.
// ---------------------------------------------------------------------------
__global__ __launch_bounds__(256) void gemm_mfma(
    const float* __restrict__ Xa, const float* __restrict__ Xb,
    const ushort_t* __restrict__ Wfrag,
    uint32* __restrict__ Pa, uint32* __restrict__ Pb,
    uint32* __restrict__ x_f8,
    int Ma, int Mb, int nblk_a) {
  __shared__ uint4 WL[2048];   // 32KB: W fragments; reused as Ys8[64][36] after
  const int blk = blockIdx.x;
  const float* X;
  const uint4* Wg;
  uint32* P;
  int M, row0;
  bool emit8;
  if (blk < nblk_a) {
    X = Xa; P = Pa; Wg = (const uint4*)Wfrag;             M = Ma; row0 = blk * 64; emit8 = true;
  } else {
    X = Xb; P = Pb; Wg = (const uint4*)(Wfrag + 16384);   M = Mb; row0 = (blk - nblk_a) * 64; emit8 = false;
  }

  const int tid = threadIdx.x;
  const int wave = tid >> 6;
  const int lane = tid & 63;
  const int m = lane & 15;
  const int quad = lane >> 4;

  // cooperative W stage via DMA: granule tid+256j -> LDS, lane*16 implicit
#pragma unroll
  for (int j = 0; j < 8; j++)
    gload_lds16(Wg + tid + 256 * j, &WL[(tid & ~63) + 256 * j]);

  const int ra = min(row0 + wave * 16 + m, M - 1);
  const float* xp = X + (size_t)ra * D128 + quad * 8;

  // issue ALL X loads (8 dwordx4 in flight per lane, HBM) under the DMA
  float4 xf[8];
#pragma unroll
  for (int kc = 0; kc < 4; kc++) {
    xf[kc * 2]     = *(const float4*)(xp + kc * 32);
    xf[kc * 2 + 1] = *(const float4*)(xp + kc * 32 + 4);
  }

  // fp8 emission + bf16 pack overlap the staging latency
  if (emit8) {
#pragma unroll
    for (int kc = 0; kc < 4; kc++) {
      uint2 q;
      q.x = pack_fp8x4(xf[kc * 2].x, xf[kc * 2].y, xf[kc * 2].z, xf[kc * 2].w);
      q.y = pack_fp8x4(xf[kc * 2 + 1].x, xf[kc * 2 + 1].y, xf[kc * 2 + 1].z, xf[kc * 2 + 1].w);
      *(uint2*)(x_f8 + (size_t)ra * 32 + kc * 8 + quad * 2) = q;
    }
  }
  bf16x8 xb[4];
#pragma unroll
  for (int kc = 0; kc < 4; kc++) xb[kc] = bf16x8_of(xf[kc * 2], xf[kc * 2 + 1]);

  __syncthreads();   // drains vmcnt -> WL complete

  f32x4 acc[8];
#pragma unroll
  for (int nt = 0; nt < 8; nt++) acc[nt] = (f32x4){0.f, 0.f, 0.f, 0.f};

#pragma unroll
  for (int kc = 0; kc < 4; kc++) {
#pragma unroll
    for (int nt = 0; nt < 8; nt++) {
      bf16x8 wf = *(const bf16x8*)&WL[(nt * 4 + kc) * 64 + lane];
      acc[nt] = __builtin_amdgcn_mfma_f32_16x16x32_bf16(wf, xb[kc], acc[nt], 0, 0, 0);
    }
  }

  __syncthreads();   // all waves done reading WL
  uint32* Ys = (uint32*)WL;   // [64][36], stride 144B
#pragma unroll
  for (int nt = 0; nt < 8; nt++)
    Ys[(wave * 16 + m) * 36 + nt * 4 + quad] =
        pack_fp8x4(acc[nt][0], acc[nt][1], acc[nt][2], acc[nt][3]);
  __syncthreads();

#pragma unroll
  for (int it = 0; it < 2; it++) {
    int f = tid + 256 * it;        // 0..511
    int row = f >> 3;
    int cu = (f & 7) * 4;
    int grow = row0 + row;
    if (grow < M) *(uint4*)(P + (size_t)grow * 32 + cu) = *(const uint4*)(&Ys[row * 36 + cu]);
  }
}

// ---------------------------------------------------------------------------
// Fused attention + aggregation, WAVE-PER-DST, SINGLE-PASS fast path:
// per 16-edge batch, issue p_src gathers (score) AND h_src gathers (agg)
// together, compute scores under the h-gather latency, then route ex to the
// agg lanes via one ds_bpermute each. Agg uses UNNORMALIZED ex; inv applied
// only at final stores (same numerics as the two-phase version).
// ---------------------------------------------------------------------------
__global__ __launch_bounds__(256) void attn_agg_kernel(
    const uint32* __restrict__ p_src_f8, const uint32* __restrict__ p_dst_f8,
    const float* __restrict__ w2, const float* __restrict__ ew,
    const int* __restrict__ src_idx, const int* __restrict__ off,
    const uint32* __restrict__ h_src_f8,
    float* __restrict__ attn_out, uint32* __restrict__ h_glob_bf, int N_dst) {
  const int tid = threadIdx.x;
  const int wv = tid >> 6;
  const int lane = tid & 63;
  const int v = blockIdx.x * 4 + wv;

  __shared__ float sex[4][SCAPW];
  __shared__ int ssrc[4][SCAPW];
  __shared__ float sew[4][SCAPW];
  if (v >= N_dst) return;

  const int lo = off[v], hi = off[v + 1];
  const int deg = hi - lo;
  const int sub = lane & 15;   // score: lane covers channels sub*8..+7
  const int eg = lane >> 4;    // score: edge slot 0..3
  const int c4 = lane & 31;    // agg: channel group c4*4..+3
  const int hw = lane >> 5;    // agg: which edge of the pair
  const bool fast = (deg <= SCAPW);

  // per-lane w2 segment + decoded p_dst segment (row wave-uniform, L1-hot)
  float4 wA = *(const float4*)(w2 + sub * 8);
  float4 wB = *(const float4*)(w2 + sub * 8 + 4);
  uint2 pdu = *(const uint2*)(p_dst_f8 + (size_t)v * 32 + sub * 2);
  f32x2 pd0 = __builtin_amdgcn_cvt_pk_f32_fp8(pdu.x, false);
  f32x2 pd1 = __builtin_amdgcn_cvt_pk_f32_fp8(pdu.x, true);
  f32x2 pd2 = __builtin_amdgcn_cvt_pk_f32_fp8(pdu.y, false);
  f32x2 pd3 = __builtin_amdgcn_cvt_pk_f32_fp8(pdu.y, true);

  float den = 0.f;
  float a0 = 0.f, a1 = 0.f, a2 = 0.f, a3 = 0.f;

  if (fast) {
    const int pad = (deg + 15) & ~15;
    // prefetch segment indices + weights (coalesced; wave-synchronous)
    for (int i = lane; i < deg; i += 64) {
      ssrc[wv][i] = src_idx[lo + i];
      sew[wv][i] = ew[lo + i];
    }
    for (int i = deg + lane; i < pad; i += 64) { ssrc[wv][i] = 0; sew[wv][i] = 0.f; }

    for (int base = 0; base < pad; base += 16) {
      // p_src gathers: 4 edges per instruction (eg groups)
      uint2 us[4];
      float ewv[4];
      int ei[4];
#pragma unroll
      for (int j = 0; j < 4; j++) {
        ei[j] = base + j * 4 + eg;
        int ss = ssrc[wv][ei[j]];
        ewv[j] = sew[wv][ei[j]];
        us[j] = *(const uint2*)(p_src_f8 + (size_t)ss * 32 + sub * 2);
      }
      // h_src gathers: 2 edges per instruction (hw split), issued EARLY so
      // their latency hides under the score VALU work below
      uint32 uh[8];
#pragma unroll
      for (int t = 0; t < 8; t++) {
        int s2 = ssrc[wv][base + 2 * t + hw];
        uh[t] = h_src_f8[(size_t)s2 * 32 + c4];
      }
      // scores (4 edges), ex kept in registers per eg-group
      float exj[4];
#pragma unroll
      for (int j = 0; j < 4; j++) {
        float sc = score8(us[j], pd0, pd1, pd2, pd3, wA, wB);
#pragma unroll
        for (int o = 1; o <= 8; o <<= 1) sc += __shfl_xor(sc, o, 64);
        float e = (ei[j] < deg) ? __expf(sc * ewv[j]) : 0.f;
        exj[j] = e;
        if (sub == 0) sex[wv][ei[j]] = e;
        den += (sub == 0) ? e : 0.f;
      }
      // aggregation: route ex[2t+hw] from its eg-group via one shuffle each
#pragma unroll
      for (int t = 0; t < 8; t++) {
        int srcl = ((((2 * t) & 3) + hw) << 4);
        float exv = __shfl(exj[t >> 1], srcl, 64);
        f32x2 h0 = __builtin_amdgcn_cvt_pk_f32_fp8(uh[t], false);
        f32x2 h1 = __builtin_amdgcn_cvt_pk_f32_fp8(uh[t], true);
        a0 = fmaf(exv, h0.x, a0);
        a1 = fmaf(exv, h0.y, a1);
        a2 = fmaf(exv, h1.x, a2);
        a3 = fmaf(exv, h1.y, a3);
      }
    }
  } else {
    // ---- slow path (deg > SCAPW): two-phase global-staged (unchanged) ----
    for (int base = 0; base < deg; base += 8) {
      const int ei0 = base + eg;
      const int ei1 = base + 4 + eg;
      const bool v0 = ei0 < deg;
      const bool v1 = ei1 < deg;
      int s0 = 0, s1 = 0;
      float ew0 = 0.f, ew1 = 0.f;
      uint2 us0, us1;
      us0.x = us0.y = us1.x = us1.y = 0u;
      if (v0) {
        const int e = lo + ei0;
        s0 = src_idx[e];
        ew0 = ew[e];
        us0 = *(const uint2*)(p_src_f8 + (size_t)s0 * 32 + sub * 2);
      }
      if (v1) {
        const int e = lo + ei1;
        s1 = src_idx[e];
        ew1 = ew[e];
        us1 = *(const uint2*)(p_src_f8 + (size_t)s1 * 32 + sub * 2);
      }
      float ex0 = 0.f, ex1 = 0.f;
      if (v0) {
        float sc = score8(us0, pd0, pd1, pd2, pd3, wA, wB);
#pragma unroll
        for (int o = 1; o <= 8; o <<= 1) sc += __shfl_xor(sc, o, 64);
        ex0 = __expf(sc * ew0);
        if (sub == 0) attn_out[lo + ei0] = ex0;
      }
      if (v1) {
        float sc = score8(us1, pd0, pd1, pd2, pd3, wA, wB);
#pragma unroll
        for (int o = 1; o <= 8; o <<= 1) sc += __shfl_xor(sc, o, 64);
        ex1 = __expf(sc * ew1);
        if (sub == 0) attn_out[lo + ei1] = ex1;
      }
      den += (sub == 0) ? (ex0 + ex1) : 0.f;
    }
  }
#pragma unroll
  for (int o = 1; o <= 32; o <<= 1) den += __shfl_xor(den, o, 64);
  const float inv = (deg > 0) ? 1.0f / den : 0.0f;

  if (fast) {
    // normalized attn from staged ex
    for (int i = lane; i < deg; i += 64) attn_out[lo + i] = sex[wv][i] * inv;
  } else {
    // slow path phase 2: gather-accumulate then normalize
    for (int b = 0; b < deg; b += 16) {
#pragma unroll
      for (int j = 0; j < 8; j++) {
        const int idx = b + j * 2 + hw;
        float ex = 0.f;
        int s = 0;
        if (idx < deg) { ex = attn_out[lo + idx]; s = src_idx[lo + idx]; }
        uint32 u = h_src_f8[(size_t)s * 32 + c4];
        f32x2 h0 = __builtin_amdgcn_cvt_pk_f32_fp8(u, false);
        f32x2 h1 = __builtin_amdgcn_cvt_pk_f32_fp8(u, true);
        a0 = fmaf(ex, h0.x, a0);
        a1 = fmaf(ex, h0.y, a1);
        a2 = fmaf(ex, h1.x, a2);
        a3 = fmaf(ex, h1.y, a3);
      }
    }
    for (int i = lane; i < deg; i += 64) attn_out[lo + i] *= inv;
  }

  // reduce the 2 edge-halves (lanes differ in bit 5)
  a0 += __shfl_xor(a0, 32, 64);
  a1 += __shfl_xor(a1, 32, 64);
  a2 += __shfl_xor(a2, 32, 64);
  a3 += __shfl_xor(a3, 32, 64);
  if (hw == 0) {   // lanes 0..31 hold channels c4*4..+3
    uint2 o;
    o.x = pack_bf2(a0 * inv, a1 * inv);
    o.y = pack_bf2(a2 * inv, a3 * inv);
    *(uint2*)(h_glob_bf + (size_t)v * 64 + c4 * 2) = o;
  }
}

// ---------------------------------------------------------------------------
// MFMA output projection + fused LayerNorm. 128 thr / 32 rows per block.
// FULL Wo_frag (64KB) staged into LDS via DMA (zero VGPR cost).
// ---------------------------------------------------------------------------
__global__ __launch_bounds__(128) void out_mfma_ln(
    const float* __restrict__ h_dst, const ushort_t* __restrict__ h_glob_bf,
    const ushort_t* __restrict__ Wo_frag,
    const float* __restrict__ bo,
    const float* __restrict__ gamma, const float* __restrict__ beta,
    float* __restrict__ y, int N) {
  __shared__ uint4 WL[4096];   // 64KB: all Wo fragments
  const int tid = threadIdx.x;
  const int w = tid >> 6;
  const int lane = tid & 63;
  const int m = lane & 15;
  const int quad = lane >> 4;
  const int row0 = blockIdx.x * 32 + w * 16;
  const int ra = min(row0 + m, N - 1);
  const uint4* Wg = (const uint4*)Wo_frag;

  // stage all 4096 granules: thread t covers t+128j (lane*16 implicit)
#pragma unroll
  for (int j = 0; j < 32; j++)
    gload_lds16(Wg + tid + 128 * j, &WL[(tid & ~63) + 128 * j]);

  // hoist all A-fragment loads (8 fp32 dwordx4 + 4 bf16 dwordx4, independent)
  float4 f0[4], f1[4];
  bf16x8 ag[4];
#pragma unroll
  for (int kc = 0; kc < 4; kc++) {
    const float* p = h_dst + (size_t)ra * D128 + kc * 32 + quad * 8;
    f0[kc] = *(const float4*)p;
    f1[kc] = *(const float4*)(p + 4);
  }
#pragma unroll
  for (int kc = 0; kc < 4; kc++)
    ag[kc] = *(const bf16x8*)(h_glob_bf + (size_t)ra * D128 + kc * 32 + quad * 8);

  // bias/gamma/beta registers for channels nt*16+m (L2-hot, reused 4x)
  float bo_r[8], gm_r[8], bt_r[8];
#pragma unroll
  for (int nt = 0; nt < 8; nt++) {
    bo_r[nt] = bo[nt * 16 + m];
    gm_r[nt] = gamma[nt * 16 + m];
    bt_r[nt] = beta[nt * 16 + m];
  }

  __syncthreads();   // drains vmcnt -> WL complete

  f32x4 acc[8];
#pragma unroll
  for (int nt = 0; nt < 8; nt++) acc[nt] = (f32x4){0.f, 0.f, 0.f, 0.f};

#pragma unroll
  for (int kc = 0; kc < 8; kc++) {
    bf16x8 a = (kc < 4) ? bf16x8_of(f0[kc & 3], f1[kc & 3]) : ag[kc & 3];
#pragma unroll
    for (int nt = 0; nt < 8; nt++) {
      bf16x8 bfr = *(const bf16x8*)&WL[(nt * 8 + kc) * 64 + lane];
      acc[nt] = __builtin_amdgcn_mfma_f32_16x16x32_bf16(a, bfr, acc[nt], 0, 0, 0);
    }
  }

#pragma unroll
  for (int r = 0; r < 4; r++) {
    const int grow = row0 + quad * 4 + r;
    const int gr = min(grow, N - 1);
    float x[8];
    float s1 = 0.f, s2 = 0.f;
#pragma unroll
    for (int nt = 0; nt < 8; nt++) {
      float hd = h_dst[(size_t)gr * D128 + nt * 16 + m];
      float xv = hd + acc[nt][r] + bo_r[nt];
      x[nt] = xv;
      s1 += xv;
      s2 = fmaf(xv, xv, s2);
    }
#pragma unroll
    for (int o = 1; o <= 8; o <<= 1) {
      s1 += __shfl_xor(s1, o, 64);
      s2 += __shfl_xor(s2, o, 64);
    }
    float mu = s1 * (1.0f / 128.0f);
    float var = s2 * (1.0f / 128.0f) - mu * mu;
    float rstd = __builtin_amdgcn_rcpf(sqrtf(var + 1e-5f));
    if (grow < N) {
#pragma unroll
      for (int nt = 0; nt < 8; nt++) {
        y[(size_t)grow * D128 + nt * 16 + m] = (x[nt] - mu) * rstd * gm_r[nt] + bt_r[nt];
      }
    }
  }
}

extern "C" void kernel_launch(void* const* d_in, const int* in_sizes, int n_in,
                              void* d_out, int out_size, void* d_ws, size_t ws_size,
                              hipStream_t stream) {
  const float* h_src = (const float*)d_in[0];
  const float* h_dst = (const float*)d_in[1];
  const float* s_emb = (const float*)d_in[2];
  const float* ew    = (const float*)d_in[3];
  const int* src_idx = (const int*)d_in[4];
  const int* dst_idx = (const int*)d_in[5];
  const float* W1    = (const float*)d_in[6];
  const float* w2    = (const float*)d_in[7];
  const float* Wo    = (const float*)d_in[8];
  const float* bo    = (const float*)d_in[9];
  const float* gamma = (const float*)d_in[10];
  const float* beta  = (const float*)d_in[11];

  const int N_src = in_sizes[0] / D128;
  const int N_dst = in_sizes[1] / D128;
  const int E = in_sizes[3];

  float* out_y = (float*)d_out;                       // [N_dst*128]
  float* out_attn = out_y + (size_t)N_dst * D128;     // [E]

  // ws layout:
  uint32* p_src_f8 = (uint32*)d_ws;                            // N_src*32 (fp8 rows)
  uint32* p_dst_f8 = p_src_f8 + (size_t)N_src * 32;            // N_dst*32
  uint32* h_src_f8 = p_dst_f8 + (size_t)N_dst * 32;            // N_src*32
  uint32* h_glob_bf = h_src_f8 + (size_t)N_src * 32;           // N_dst*64 (bf16)
  int* seg_off = (int*)(h_glob_bf + (size_t)N_dst * 64);       // N_dst+1
  ushort_t* Wfrag = (ushort_t*)(seg_off + N_dst + 1 + 3);      // 32768 shorts
  ushort_t* Wo_frag = Wfrag + 32768;                           // 32768 shorts

  const int nblk_a = (N_src + 63) / 64;
  const int nblk_b = (N_dst + 63) / 64;
  const int nb_seg = (E + 255) / 256;

  prep_all<<<32 + nb_seg, 256, 0, stream>>>(
      W1, Wo, dst_idx, Wfrag, Wo_frag, seg_off, E, N_dst);
  gemm_mfma<<<nblk_a + nblk_b, 256, 0, stream>>>(
      h_src, s_emb, Wfrag, p_src_f8, p_dst_f8, h_src_f8, N_src, N_dst, nblk_a);
  attn_agg_kernel<<<(N_dst + 3) / 4, 256, 0, stream>>>(
      p_src_f8, p_dst_f8, w2, ew, src_idx, seg_off, h_src_f8, out_attn,
      h_glob_bf, N_dst);
  out_mfma_ln<<<(N_dst + 31) / 32, 128, 0, stream>>>(
      h_dst, (const ushort_t*)h_glob_bf, Wo_frag,
      bo, gamma, beta, out_y, N_dst);
}

// Round 9
// 162.398 us; speedup vs baseline: 1.0010x; 1.0010x over previous
//
#include <hip/hip_runtime.h>
#include <math.h>

#define D128 128
#define SCAPW 256   // per-wave LDS score capacity (deg ~ Poisson(32); P(deg>256)~0)

typedef unsigned int uint32;
typedef unsigned short ushort_t;
typedef short bf16x8 __attribute__((ext_vector_type(8)));
typedef float f32x4 __attribute__((ext_vector_type(4)));
typedef float f32x2 __attribute__((ext_vector_type(2)));

// fp32 -> bf16 (RNE)
__device__ __forceinline__ ushort_t bf16_of(float x) {
  uint32 u = __float_as_uint(x);
  return (ushort_t)((u + 0x7fffu + ((u >> 16) & 1u)) >> 16);
}
__device__ __forceinline__ uint32 pack_bf2(float x, float y) {
  uint32 bx = __float_as_uint(x);
  uint32 by = __float_as_uint(y);
  bx = (bx + 0x7fffu + ((bx >> 16) & 1u)) >> 16;
  by = (by + 0x7fffu + ((by >> 16) & 1u)) & 0xffff0000u;
  return bx | by;
}

// tanh(x) = 1 - 2/(1+exp(2x)); exp(2x) folded to one v_mul + v_exp (exp2)
__device__ __forceinline__ float fast_tanh(float x) {
  float e = __builtin_exp2f(x * 2.8853900817779268f);
  float r = __builtin_amdgcn_rcpf(1.0f + e);
  return fmaf(-2.0f, r, 1.0f);
}

// pack 4 fp32 -> 4 OCP e4m3 fp8 in one uint (HW RNE)
__device__ __forceinline__ uint32 pack_fp8x4(float a, float b, float c, float d) {
  int u = __builtin_amdgcn_cvt_pk_fp8_f32(a, b, 0, false);
  u = __builtin_amdgcn_cvt_pk_fp8_f32(c, d, u, true);
  return (uint32)u;
}

// pack 8 consecutive fp32 (two float4) -> bf16x8 (memory order)
__device__ __forceinline__ bf16x8 bf16x8_of(float4 a, float4 c) {
  union { uint4 u; bf16x8 h; } r;
  r.u.x = pack_bf2(a.x, a.y);
  r.u.y = pack_bf2(a.z, a.w);
  r.u.z = pack_bf2(c.x, c.y);
  r.u.w = pack_bf2(c.z, c.w);
  return r.h;
}

// direct global->LDS DMA, 16B per lane (wave-uniform LDS base + lane*16)
__device__ __forceinline__ void gload_lds16(const void* g, void* l) {
  __builtin_amdgcn_global_load_lds(
      (const __attribute__((address_space(1))) unsigned int*)g,
      (__attribute__((address_space(3))) unsigned int*)l, 16, 0, 0);
}

// 8-channel tanh-weighted partial score from one fp8 row segment
__device__ __forceinline__ float score8(uint2 us, f32x2 pd0, f32x2 pd1, f32x2 pd2,
                                        f32x2 pd3, float4 wA, float4 wB) {
  f32x2 a0 = __builtin_amdgcn_cvt_pk_f32_fp8(us.x, false);
  f32x2 a1 = __builtin_amdgcn_cvt_pk_f32_fp8(us.x, true);
  f32x2 a2 = __builtin_amdgcn_cvt_pk_f32_fp8(us.y, false);
  f32x2 a3 = __builtin_amdgcn_cvt_pk_f32_fp8(us.y, true);
  float sc;
  sc = fast_tanh(a0.x + pd0.x) * wA.x;
  sc = fmaf(fast_tanh(a0.y + pd0.y), wA.y, sc);
  sc = fmaf(fast_tanh(a1.x + pd1.x), wA.z, sc);
  sc = fmaf(fast_tanh(a1.y + pd1.y), wA.w, sc);
  sc = fmaf(fast_tanh(a2.x + pd2.x), wB.x, sc);
  sc = fmaf(fast_tanh(a2.y + pd2.y), wB.y, sc);
  sc = fmaf(fast_tanh(a3.x + pd3.x), wB.z, sc);
  sc = fmaf(fast_tanh(a3.y + pd3.y), wB.w, sc);
  return sc;
}

// ---------------------------------------------------------------------------
// prep_all: W fragments + segment offsets only.
// ---------------------------------------------------------------------------
__global__ __launch_bounds__(256) void prep_all(
    const float* __restrict__ W1, const float* __restrict__ Wo,
    const int* __restrict__ dst_idx,
    ushort_t* __restrict__ Wfrag, ushort_t* __restrict__ Wo_frag,
    int* __restrict__ off, int E, int N) {
  const int b = blockIdx.x;
  const int tid = threadIdx.x;
  if (b < 16) {
    // W1 fragments: t indexes [h][nt][kc][lane]; frag[j]=W1[k][n] (k=quad*8+j)
    int t = b * 256 + tid;   // 0..4095
    int lane = t & 63;
    int kc = (t >> 6) & 3;
    int nt = (t >> 8) & 7;
    int h = (t >> 11) & 1;
    int m = lane & 15;
    int quad = lane >> 4;
    int krow = h * D128 + kc * 32 + quad * 8;
    int ncol = nt * 16 + m;
    ushort_t fr[8];
#pragma unroll
    for (int j = 0; j < 8; j++) fr[j] = bf16_of(W1[(size_t)(krow + j) * D128 + ncol]);
    *(uint4*)(Wfrag + (size_t)t * 8) = *(const uint4*)fr;
  } else if (b < 32) {
    // Wo fragments: t indexes [nt][kc8][lane], kc8 0..7 (K=256)
    int t = (b - 16) * 256 + tid;   // 0..4095
    int lane = t & 63;
    int kc = (t >> 6) & 7;
    int nt = (t >> 9) & 7;
    int m = lane & 15;
    int quad = lane >> 4;
    int krow = kc * 32 + quad * 8;
    int ncol = nt * 16 + m;
    ushort_t fr[8];
#pragma unroll
    for (int j = 0; j < 8; j++) fr[j] = bf16_of(Wo[(size_t)(krow + j) * D128 + ncol]);
    *(uint4*)(Wo_frag + (size_t)t * 8) = *(const uint4*)fr;
  } else {
    int e = (b - 32) * 256 + tid;
    if (e >= E) return;
    int d = dst_idx[e];
    int dprev = (e == 0) ? -1 : dst_idx[e - 1];
    for (int v = dprev + 1; v <= d; v++) off[v] = e;
    if (e == E - 1) {
      for (int v = d + 1; v <= N; v++) off[v] = E;
    }
  }
}

// ---------------------------------------------------------------------------
// Merged GEMM, fp8 output. 64-row tiles; W half staged once/block into LDS
// via global_load_lds DMA (no VGPR round trip); LDS reused for the fp8
// repack epilogue.
// ---------------------------------------------------------------------------
__global__ __launch_bounds__(256) void gemm_mfma(
    const float* __restrict__ Xa, const float* __restrict__ Xb,
    const ushort_t* __restrict__ Wfrag,
    uint32* __restrict__ Pa, uint32* __restrict__ Pb,
    uint32* __restrict__ x_f8,
    int Ma, int Mb, int nblk_a) {
  __shared__ uint4 WL[2048];   // 32KB: W fragments; reused as Ys8[64][36] after
  const int blk = blockIdx.x;
  const float* X;
  const uint4* Wg;
  uint32* P;
  int M, row0;
  bool emit8;
  if (blk < nblk_a) {
    X = Xa; P = Pa; Wg = (const uint4*)Wfrag;             M = Ma; row0 = blk * 64; emit8 = true;
  } else {
    X = Xb; P = Pb; Wg = (const uint4*)(Wfrag + 16384);   M = Mb; row0 = (blk - nblk_a) * 64; emit8 = false;
  }

  const int tid = threadIdx.x;
  const int wave = tid >> 6;
  const int lane = tid & 63;
  const int m = lane & 15;
  const int quad = lane >> 4;

  // cooperative W stage via DMA: granule tid+256j -> LDS, lane*16 implicit
#pragma unroll
  for (int j = 0; j < 8; j++)
    gload_lds16(Wg + tid + 256 * j, &WL[(tid & ~63) + 256 * j]);

  const int ra = min(row0 + wave * 16 + m, M - 1);
  const float* xp = X + (size_t)ra * D128 + quad * 8;

  // issue ALL X loads (8 dwordx4 in flight per lane, HBM) under the DMA
  float4 xf[8];
#pragma unroll
  for (int kc = 0; kc < 4; kc++) {
    xf[kc * 2]     = *(const float4*)(xp + kc * 32);
    xf[kc * 2 + 1] = *(const float4*)(xp + kc * 32 + 4);
  }

  // fp8 emission + bf16 pack overlap the staging latency
  if (emit8) {
#pragma unroll
    for (int kc = 0; kc < 4; kc++) {
      uint2 q;
      q.x = pack_fp8x4(xf[kc * 2].x, xf[kc * 2].y, xf[kc * 2].z, xf[kc * 2].w);
      q.y = pack_fp8x4(xf[kc * 2 + 1].x, xf[kc * 2 + 1].y, xf[kc * 2 + 1].z, xf[kc * 2 + 1].w);
      *(uint2*)(x_f8 + (size_t)ra * 32 + kc * 8 + quad * 2) = q;
    }
  }
  bf16x8 xb[4];
#pragma unroll
  for (int kc = 0; kc < 4; kc++) xb[kc] = bf16x8_of(xf[kc * 2], xf[kc * 2 + 1]);

  __syncthreads();   // drains vmcnt -> WL complete

  f32x4 acc[8];
#pragma unroll
  for (int nt = 0; nt < 8; nt++) acc[nt] = (f32x4){0.f, 0.f, 0.f, 0.f};

#pragma unroll
  for (int kc = 0; kc < 4; kc++) {
#pragma unroll
    for (int nt = 0; nt < 8; nt++) {
      bf16x8 wf = *(const bf16x8*)&WL[(nt * 4 + kc) * 64 + lane];
      acc[nt] = __builtin_amdgcn_mfma_f32_16x16x32_bf16(wf, xb[kc], acc[nt], 0, 0, 0);
    }
  }

  __syncthreads();   // all waves done reading WL
  uint32* Ys = (uint32*)WL;   // [64][36], stride 144B
#pragma unroll
  for (int nt = 0; nt < 8; nt++)
    Ys[(wave * 16 + m) * 36 + nt * 4 + quad] =
        pack_fp8x4(acc[nt][0], acc[nt][1], acc[nt][2], acc[nt][3]);
  __syncthreads();

#pragma unroll
  for (int it = 0; it < 2; it++) {
    int f = tid + 256 * it;        // 0..511
    int row = f >> 3;
    int cu = (f & 7) * 4;
    int grow = row0 + row;
    if (grow < M) *(uint4*)(P + (size_t)grow * 32 + cu) = *(const uint4*)(&Ys[row * 36 + cu]);
  }
}

// ---------------------------------------------------------------------------
// Fused attention + aggregation, WAVE-PER-DST, TWO-PHASE, fp8 tables.
// Segment src_idx/ew prefetched into LDS (coalesced, wave-synchronous);
// phase 1 x4 unrolled -> 4 p_src row-gathers in flight.
// Phase 2 (agg): 32 lanes per fp8 row, 8 gathers in flight per lane.
// (R7 structure — verified best; R8's single-pass fusion regressed.)
// ---------------------------------------------------------------------------
__global__ __launch_bounds__(256) void attn_agg_kernel(
    const uint32* __restrict__ p_src_f8, const uint32* __restrict__ p_dst_f8,
    const float* __restrict__ w2, const float* __restrict__ ew,
    const int* __restrict__ src_idx, const int* __restrict__ off,
    const uint32* __restrict__ h_src_f8,
    float* __restrict__ attn_out, uint32* __restrict__ h_glob_bf, int N_dst) {
  const int tid = threadIdx.x;
  const int wv = tid >> 6;
  const int lane = tid & 63;
  const int v = blockIdx.x * 4 + wv;

  __shared__ float sex[4][SCAPW];
  __shared__ int ssrc[4][SCAPW];
  __shared__ float sew[4][SCAPW];
  if (v >= N_dst) return;

  const int lo = off[v], hi = off[v + 1];
  const int deg = hi - lo;
  const int sub = lane & 15;   // lane covers channels sub*8..+7 (score)
  const int eg = lane >> 4;    // edge slot 0..3 (score)
  const bool fast = (deg <= SCAPW);

  // per-lane w2 segment + decoded p_dst segment (row wave-uniform, L1-hot)
  float4 wA = *(const float4*)(w2 + sub * 8);
  float4 wB = *(const float4*)(w2 + sub * 8 + 4);
  uint2 pdu = *(const uint2*)(p_dst_f8 + (size_t)v * 32 + sub * 2);
  f32x2 pd0 = __builtin_amdgcn_cvt_pk_f32_fp8(pdu.x, false);
  f32x2 pd1 = __builtin_amdgcn_cvt_pk_f32_fp8(pdu.x, true);
  f32x2 pd2 = __builtin_amdgcn_cvt_pk_f32_fp8(pdu.y, false);
  f32x2 pd3 = __builtin_amdgcn_cvt_pk_f32_fp8(pdu.y, true);

  float den = 0.f;

  if (fast) {
    // prefetch segment indices + weights (coalesced; wave-synchronous,
    // producer == consumer wave, no barrier needed)
    for (int i = lane; i < deg; i += 64) {
      ssrc[wv][i] = src_idx[lo + i];
      sew[wv][i] = ew[lo + i];
    }
    // ---- phase 1: scores, x4 unrolled (4 row-gathers in flight) ----
    for (int base = 0; base < deg; base += 16) {
      int ei[4], ss[4];
      float ewv[4];
      uint2 us[4];
      bool vl[4];
#pragma unroll
      for (int j = 0; j < 4; j++) {
        ei[j] = base + j * 4 + eg;
        vl[j] = ei[j] < deg;
        const int ii = vl[j] ? ei[j] : 0;
        ss[j] = ssrc[wv][ii];
        ewv[j] = sew[wv][ii];
        us[j] = *(const uint2*)(p_src_f8 + (size_t)ss[j] * 32 + sub * 2);
      }
#pragma unroll
      for (int j = 0; j < 4; j++) {
        if (!vl[j]) continue;
        float sc = score8(us[j], pd0, pd1, pd2, pd3, wA, wB);
#pragma unroll
        for (int o = 1; o <= 8; o <<= 1) sc += __shfl_xor(sc, o, 64);
        float e = __expf(sc * ewv[j]);
        if (sub == 0) sex[wv][ei[j]] = e;
        den += (sub == 0) ? e : 0.f;
      }
    }
  } else {
    // ---- slow path (deg > SCAPW): original global-staged loop ----
    for (int base = 0; base < deg; base += 8) {
      const int ei0 = base + eg;
      const int ei1 = base + 4 + eg;
      const bool v0 = ei0 < deg;
      const bool v1 = ei1 < deg;
      int s0 = 0, s1 = 0;
      float ew0 = 0.f, ew1 = 0.f;
      uint2 us0, us1;
      us0.x = us0.y = us1.x = us1.y = 0u;
      if (v0) {
        const int e = lo + ei0;
        s0 = src_idx[e];
        ew0 = ew[e];
        us0 = *(const uint2*)(p_src_f8 + (size_t)s0 * 32 + sub * 2);
      }
      if (v1) {
        const int e = lo + ei1;
        s1 = src_idx[e];
        ew1 = ew[e];
        us1 = *(const uint2*)(p_src_f8 + (size_t)s1 * 32 + sub * 2);
      }
      float ex0 = 0.f, ex1 = 0.f;
      if (v0) {
        float sc = score8(us0, pd0, pd1, pd2, pd3, wA, wB);
#pragma unroll
        for (int o = 1; o <= 8; o <<= 1) sc += __shfl_xor(sc, o, 64);
        ex0 = __expf(sc * ew0);
        if (sub == 0) attn_out[lo + ei0] = ex0;
      }
      if (v1) {
        float sc = score8(us1, pd0, pd1, pd2, pd3, wA, wB);
#pragma unroll
        for (int o = 1; o <= 8; o <<= 1) sc += __shfl_xor(sc, o, 64);
        ex1 = __expf(sc * ew1);
        if (sub == 0) attn_out[lo + ei1] = ex1;
      }
      den += (sub == 0) ? (ex0 + ex1) : 0.f;
    }
  }
#pragma unroll
  for (int o = 1; o <= 32; o <<= 1) den += __shfl_xor(den, o, 64);
  const float inv = (deg > 0) ? 1.0f / den : 0.0f;

  // ---- phase 2: aggregation (32 lanes per fp8 row, 2 edges per step) ----
  const int c4 = lane & 31;    // channel group: channels c4*4..+3
  const int hw = lane >> 5;    // which edge of the pair
  float a0 = 0.f, a1 = 0.f, a2 = 0.f, a3 = 0.f;

  if (fast) {
    const int pad = (deg + 15) & ~15;
    for (int i = deg + lane; i < pad; i += 64) { sex[wv][i] = 0.f; ssrc[wv][i] = 0; }
    for (int i = lane; i < deg; i += 64) attn_out[lo + i] = sex[wv][i] * inv;
    for (int b = 0; b < pad; b += 16) {
#pragma unroll
      for (int j = 0; j < 8; j++) {
        const int idx = b + j * 2 + hw;
        float ex = sex[wv][idx];
        int s = ssrc[wv][idx];
        uint32 u = h_src_f8[(size_t)s * 32 + c4];
        f32x2 h0 = __builtin_amdgcn_cvt_pk_f32_fp8(u, false);
        f32x2 h1 = __builtin_amdgcn_cvt_pk_f32_fp8(u, true);
        a0 = fmaf(ex, h0.x, a0);
        a1 = fmaf(ex, h0.y, a1);
        a2 = fmaf(ex, h1.x, a2);
        a3 = fmaf(ex, h1.y, a3);
      }
    }
  } else {
    for (int b = 0; b < deg; b += 16) {
#pragma unroll
      for (int j = 0; j < 8; j++) {
        const int idx = b + j * 2 + hw;
        float ex = 0.f;
        int s = 0;
        if (idx < deg) { ex = attn_out[lo + idx]; s = src_idx[lo + idx]; }
        uint32 u = h_src_f8[(size_t)s * 32 + c4];
        f32x2 h0 = __builtin_amdgcn_cvt_pk_f32_fp8(u, false);
        f32x2 h1 = __builtin_amdgcn_cvt_pk_f32_fp8(u, true);
        a0 = fmaf(ex, h0.x, a0);
        a1 = fmaf(ex, h0.y, a1);
        a2 = fmaf(ex, h1.x, a2);
        a3 = fmaf(ex, h1.y, a3);
      }
    }
    // normalize attn AFTER all reads (same wave, sequential)
    for (int i = lane; i < deg; i += 64) attn_out[lo + i] *= inv;
  }

  // reduce the 2 edge-halves (lanes differ in bit 5)
  a0 += __shfl_xor(a0, 32, 64);
  a1 += __shfl_xor(a1, 32, 64);
  a2 += __shfl_xor(a2, 32, 64);
  a3 += __shfl_xor(a3, 32, 64);
  if (hw == 0) {   // lanes 0..31 hold channels c4*4..+3
    uint2 o;
    o.x = pack_bf2(a0 * inv, a1 * inv);
    o.y = pack_bf2(a2 * inv, a3 * inv);
    *(uint2*)(h_glob_bf + (size_t)v * 64 + c4 * 2) = o;
  }
}

// ---------------------------------------------------------------------------
// MFMA output projection + fused LayerNorm. 256 thr / 64 rows per block:
// the 64KB Wo DMA stage is split across 4 waves (16 granules/thread instead
// of 32), quartering the per-wave serial DMA issue chain and halving total
// Wo L2 re-reads. Per-wave MFMA/LN work unchanged (16 rows per wave).
// ---------------------------------------------------------------------------
__global__ __launch_bounds__(256) void out_mfma_ln(
    const float* __restrict__ h_dst, const ushort_t* __restrict__ h_glob_bf,
    const ushort_t* __restrict__ Wo_frag,
    const float* __restrict__ bo,
    const float* __restrict__ gamma, const float* __restrict__ beta,
    float* __restrict__ y, int N) {
  __shared__ uint4 WL[4096];   // 64KB: all Wo fragments
  const int tid = threadIdx.x;
  const int w = tid >> 6;
  const int lane = tid & 63;
  const int m = lane & 15;
  const int quad = lane >> 4;
  const int row0 = blockIdx.x * 64 + w * 16;
  const int ra = min(row0 + m, N - 1);
  const uint4* Wg = (const uint4*)Wo_frag;

  // stage all 4096 granules cooperatively: thread t covers t+256j
#pragma unroll
  for (int j = 0; j < 16; j++)
    gload_lds16(Wg + tid + 256 * j, &WL[(tid & ~63) + 256 * j]);

  // hoist all A-fragment loads (8 fp32 dwordx4 + 4 bf16 dwordx4, independent)
  float4 f0[4], f1[4];
  bf16x8 ag[4];
#pragma unroll
  for (int kc = 0; kc < 4; kc++) {
    const float* p = h_dst + (size_t)ra * D128 + kc * 32 + quad * 8;
    f0[kc] = *(const float4*)p;
    f1[kc] = *(const float4*)(p + 4);
  }
#pragma unroll
  for (int kc = 0; kc < 4; kc++)
    ag[kc] = *(const bf16x8*)(h_glob_bf + (size_t)ra * D128 + kc * 32 + quad * 8);

  // bias/gamma/beta registers for channels nt*16+m (L2-hot, reused 4x)
  float bo_r[8], gm_r[8], bt_r[8];
#pragma unroll
  for (int nt = 0; nt < 8; nt++) {
    bo_r[nt] = bo[nt * 16 + m];
    gm_r[nt] = gamma[nt * 16 + m];
    bt_r[nt] = beta[nt * 16 + m];
  }

  __syncthreads();   // drains vmcnt -> WL complete

  f32x4 acc[8];
#pragma unroll
  for (int nt = 0; nt < 8; nt++) acc[nt] = (f32x4){0.f, 0.f, 0.f, 0.f};

#pragma unroll
  for (int kc = 0; kc < 8; kc++) {
    bf16x8 a = (kc < 4) ? bf16x8_of(f0[kc & 3], f1[kc & 3]) : ag[kc & 3];
#pragma unroll
    for (int nt = 0; nt < 8; nt++) {
      bf16x8 bfr = *(const bf16x8*)&WL[(nt * 8 + kc) * 64 + lane];
      acc[nt] = __builtin_amdgcn_mfma_f32_16x16x32_bf16(a, bfr, acc[nt], 0, 0, 0);
    }
  }

#pragma unroll
  for (int r = 0; r < 4; r++) {
    const int grow = row0 + quad * 4 + r;
    const int gr = min(grow, N - 1);
    float x[8];
    float s1 = 0.f, s2 = 0.f;
#pragma unroll
    for (int nt = 0; nt < 8; nt++) {
      float hd = h_dst[(size_t)gr * D128 + nt * 16 + m];
      float xv = hd + acc[nt][r] + bo_r[nt];
      x[nt] = xv;
      s1 += xv;
      s2 = fmaf(xv, xv, s2);
    }
#pragma unroll
    for (int o = 1; o <= 8; o <<= 1) {
      s1 += __shfl_xor(s1, o, 64);
      s2 += __shfl_xor(s2, o, 64);
    }
    float mu = s1 * (1.0f / 128.0f);
    float var = s2 * (1.0f / 128.0f) - mu * mu;
    float rstd = __builtin_amdgcn_rcpf(sqrtf(var + 1e-5f));
    if (grow < N) {
#pragma unroll
      for (int nt = 0; nt < 8; nt++) {
        y[(size_t)grow * D128 + nt * 16 + m] = (x[nt] - mu) * rstd * gm_r[nt] + bt_r[nt];
      }
    }
  }
}

extern "C" void kernel_launch(void* const* d_in, const int* in_sizes, int n_in,
                              void* d_out, int out_size, void* d_ws, size_t ws_size,
                              hipStream_t stream) {
  const float* h_src = (const float*)d_in[0];
  const float* h_dst = (const float*)d_in[1];
  const float* s_emb = (const float*)d_in[2];
  const float* ew    = (const float*)d_in[3];
  const int* src_idx = (const int*)d_in[4];
  const int* dst_idx = (const int*)d_in[5];
  const float* W1    = (const float*)d_in[6];
  const float* w2    = (const float*)d_in[7];
  const float* Wo    = (const float*)d_in[8];
  const float* bo    = (const float*)d_in[9];
  const float* gamma = (const float*)d_in[10];
  const float* beta  = (const float*)d_in[11];

  const int N_src = in_sizes[0] / D128;
  const int N_dst = in_sizes[1] / D128;
  const int E = in_sizes[3];

  float* out_y = (float*)d_out;                       // [N_dst*128]
  float* out_attn = out_y + (size_t)N_dst * D128;     // [E]

  // ws layout:
  uint32* p_src_f8 = (uint32*)d_ws;                            // N_src*32 (fp8 rows)
  uint32* p_dst_f8 = p_src_f8 + (size_t)N_src * 32;            // N_dst*32
  uint32* h_src_f8 = p_dst_f8 + (size_t)N_dst * 32;            // N_src*32
  uint32* h_glob_bf = h_src_f8 + (size_t)N_src * 32;           // N_dst*64 (bf16)
  int* seg_off = (int*)(h_glob_bf + (size_t)N_dst * 64);       // N_dst+1
  ushort_t* Wfrag = (ushort_t*)(seg_off + N_dst + 1 + 3);      // 32768 shorts
  ushort_t* Wo_frag = Wfrag + 32768;                           // 32768 shorts

  const int nblk_a = (N_src + 63) / 64;
  const int nblk_b = (N_dst + 63) / 64;
  const int nb_seg = (E + 255) / 256;

  prep_all<<<32 + nb_seg, 256, 0, stream>>>(
      W1, Wo, dst_idx, Wfrag, Wo_frag, seg_off, E, N_dst);
  gemm_mfma<<<nblk_a + nblk_b, 256, 0, stream>>>(
      h_src, s_emb, Wfrag, p_src_f8, p_dst_f8, h_src_f8, N_src, N_dst, nblk_a);
  attn_agg_kernel<<<(N_dst + 3) / 4, 256, 0, stream>>>(
      p_src_f8, p_dst_f8, w2, ew, src_idx, seg_off, h_src_f8, out_attn,
      h_glob_bf, N_dst);
  out_mfma_ln<<<(N_dst + 63) / 64, 256, 0, stream>>>(
      h_dst, (const ushort_t*)h_glob_bf, Wo_frag,
      bo, gamma, beta, out_y, N_dst);
}

// Round 10
// 157.044 us; speedup vs baseline: 1.0351x; 1.0341x over previous
//
#include <hip/hip_runtime.h>
#include <math.h>

#define D128 128
#define SCAPW 256   // per-wave LDS score capacity (deg ~ Poisson(32); P(deg>256)~0)

typedef unsigned int uint32;
typedef unsigned short ushort_t;
typedef short bf16x8 __attribute__((ext_vector_type(8)));
typedef float f32x4 __attribute__((ext_vector_type(4)));
typedef float f32x2 __attribute__((ext_vector_type(2)));

// fp32 -> bf16 (RNE)
__device__ __forceinline__ ushort_t bf16_of(float x) {
  uint32 u = __float_as_uint(x);
  return (ushort_t)((u + 0x7fffu + ((u >> 16) & 1u)) >> 16);
}
__device__ __forceinline__ uint32 pack_bf2(float x, float y) {
  uint32 bx = __float_as_uint(x);
  uint32 by = __float_as_uint(y);
  bx = (bx + 0x7fffu + ((bx >> 16) & 1u)) >> 16;
  by = (by + 0x7fffu + ((by >> 16) & 1u)) & 0xffff0000u;
  return bx | by;
}

// tanh(x) = 1 - 2/(1+exp(2x)) via v_exp + v_rcp
__device__ __forceinline__ float fast_tanh(float x) {
  float e = __expf(2.0f * x);
  float r = __builtin_amdgcn_rcpf(1.0f + e);
  return fmaf(-2.0f, r, 1.0f);
}

// pack 4 fp32 -> 4 OCP e4m3 fp8 in one uint (HW RNE)
__device__ __forceinline__ uint32 pack_fp8x4(float a, float b, float c, float d) {
  int u = __builtin_amdgcn_cvt_pk_fp8_f32(a, b, 0, false);
  u = __builtin_amdgcn_cvt_pk_fp8_f32(c, d, u, true);
  return (uint32)u;
}

// pack 8 consecutive fp32 (two float4) -> bf16x8 (memory order)
__device__ __forceinline__ bf16x8 bf16x8_of(float4 a, float4 c) {
  union { uint4 u; bf16x8 h; } r;
  r.u.x = pack_bf2(a.x, a.y);
  r.u.y = pack_bf2(a.z, a.w);
  r.u.z = pack_bf2(c.x, c.y);
  r.u.w = pack_bf2(c.z, c.w);
  return r.h;
}

// direct global->LDS DMA, 16B per lane (wave-uniform LDS base + lane*16)
__device__ __forceinline__ void gload_lds16(const void* g, void* l) {
  __builtin_amdgcn_global_load_lds(
      (const __attribute__((address_space(1))) unsigned int*)g,
      (__attribute__((address_space(3))) unsigned int*)l, 16, 0, 0);
}

// 8-channel tanh-weighted partial score from one fp8 row segment
__device__ __forceinline__ float score8(uint2 us, f32x2 pd0, f32x2 pd1, f32x2 pd2,
                                        f32x2 pd3, float4 wA, float4 wB) {
  f32x2 a0 = __builtin_amdgcn_cvt_pk_f32_fp8(us.x, false);
  f32x2 a1 = __builtin_amdgcn_cvt_pk_f32_fp8(us.x, true);
  f32x2 a2 = __builtin_amdgcn_cvt_pk_f32_fp8(us.y, false);
  f32x2 a3 = __builtin_amdgcn_cvt_pk_f32_fp8(us.y, true);
  float sc;
  sc = fast_tanh(a0.x + pd0.x) * wA.x;
  sc = fmaf(fast_tanh(a0.y + pd0.y), wA.y, sc);
  sc = fmaf(fast_tanh(a1.x + pd1.x), wA.z, sc);
  sc = fmaf(fast_tanh(a1.y + pd1.y), wA.w, sc);
  sc = fmaf(fast_tanh(a2.x + pd2.x), wB.x, sc);
  sc = fmaf(fast_tanh(a2.y + pd2.y), wB.y, sc);
  sc = fmaf(fast_tanh(a3.x + pd3.x), wB.z, sc);
  sc = fmaf(fast_tanh(a3.y + pd3.y), wB.w, sc);
  return sc;
}

// ---------------------------------------------------------------------------
// prep_all: W fragments + segment offsets only.
// ---------------------------------------------------------------------------
__global__ __launch_bounds__(256) void prep_all(
    const float* __restrict__ W1, const float* __restrict__ Wo,
    const int* __restrict__ dst_idx,
    ushort_t* __restrict__ Wfrag, ushort_t* __restrict__ Wo_frag,
    int* __restrict__ off, int E, int N) {
  const int b = blockIdx.x;
  const int tid = threadIdx.x;
  if (b < 16) {
    // W1 fragments: t indexes [h][nt][kc][lane]; frag[j]=W1[k][n] (k=quad*8+j)
    int t = b * 256 + tid;   // 0..4095
    int lane = t & 63;
    int kc = (t >> 6) & 3;
    int nt = (t >> 8) & 7;
    int h = (t >> 11) & 1;
    int m = lane & 15;
    int quad = lane >> 4;
    int krow = h * D128 + kc * 32 + quad * 8;
    int ncol = nt * 16 + m;
    ushort_t fr[8];
#pragma unroll
    for (int j = 0; j < 8; j++) fr[j] = bf16_of(W1[(size_t)(krow + j) * D128 + ncol]);
    *(uint4*)(Wfrag + (size_t)t * 8) = *(const uint4*)fr;
  } else if (b < 32) {
    // Wo fragments: t indexes [nt][kc8][lane], kc8 0..7 (K=256)
    int t = (b - 16) * 256 + tid;   // 0..4095
    int lane = t & 63;
    int kc = (t >> 6) & 7;
    int nt = (t >> 9) & 7;
    int m = lane & 15;
    int quad = lane >> 4;
    int krow = kc * 32 + quad * 8;
    int ncol = nt * 16 + m;
    ushort_t fr[8];
#pragma unroll
    for (int j = 0; j < 8; j++) fr[j] = bf16_of(Wo[(size_t)(krow + j) * D128 + ncol]);
    *(uint4*)(Wo_frag + (size_t)t * 8) = *(const uint4*)fr;
  } else {
    int e = (b - 32) * 256 + tid;
    if (e >= E) return;
    int d = dst_idx[e];
    int dprev = (e == 0) ? -1 : dst_idx[e - 1];
    for (int v = dprev + 1; v <= d; v++) off[v] = e;
    if (e == E - 1) {
      for (int v = d + 1; v <= N; v++) off[v] = E;
    }
  }
}

// ---------------------------------------------------------------------------
// Merged GEMM, fp8 output. 64-row tiles; W half staged once/block into LDS
// via global_load_lds DMA (no VGPR round trip); LDS reused for the fp8
// repack epilogue.
// ---------------------------------------------------------------------------
__global__ __launch_bounds__(256) void gemm_mfma(
    const float* __restrict__ Xa, const float* __restrict__ Xb,
    const ushort_t* __restrict__ Wfrag,
    uint32* __restrict__ Pa, uint32* __restrict__ Pb,
    uint32* __restrict__ x_f8,
    int Ma, int Mb, int nblk_a) {
  __shared__ uint4 WL[2048];   // 32KB: W fragments; reused as Ys8[64][36] after
  const int blk = blockIdx.x;
  const float* X;
  const uint4* Wg;
  uint32* P;
  int M, row0;
  bool emit8;
  if (blk < nblk_a) {
    X = Xa; P = Pa; Wg = (const uint4*)Wfrag;             M = Ma; row0 = blk * 64; emit8 = true;
  } else {
    X = Xb; P = Pb; Wg = (const uint4*)(Wfrag + 16384);   M = Mb; row0 = (blk - nblk_a) * 64; emit8 = false;
  }

  const int tid = threadIdx.x;
  const int wave = tid >> 6;
  const int lane = tid & 63;
  const int m = lane & 15;
  const int quad = lane >> 4;

  // cooperative W stage via DMA: granule tid+256j -> LDS, lane*16 implicit
#pragma unroll
  for (int j = 0; j < 8; j++)
    gload_lds16(Wg + tid + 256 * j, &WL[(tid & ~63) + 256 * j]);

  const int ra = min(row0 + wave * 16 + m, M - 1);
  const float* xp = X + (size_t)ra * D128 + quad * 8;

  // issue ALL X loads (8 dwordx4 in flight per lane, HBM) under the DMA
  float4 xf[8];
#pragma unroll
  for (int kc = 0; kc < 4; kc++) {
    xf[kc * 2]     = *(const float4*)(xp + kc * 32);
    xf[kc * 2 + 1] = *(const float4*)(xp + kc * 32 + 4);
  }

  // fp8 emission + bf16 pack overlap the staging latency
  if (emit8) {
#pragma unroll
    for (int kc = 0; kc < 4; kc++) {
      uint2 q;
      q.x = pack_fp8x4(xf[kc * 2].x, xf[kc * 2].y, xf[kc * 2].z, xf[kc * 2].w);
      q.y = pack_fp8x4(xf[kc * 2 + 1].x, xf[kc * 2 + 1].y, xf[kc * 2 + 1].z, xf[kc * 2 + 1].w);
      *(uint2*)(x_f8 + (size_t)ra * 32 + kc * 8 + quad * 2) = q;
    }
  }
  bf16x8 xb[4];
#pragma unroll
  for (int kc = 0; kc < 4; kc++) xb[kc] = bf16x8_of(xf[kc * 2], xf[kc * 2 + 1]);

  __syncthreads();   // drains vmcnt -> WL complete

  f32x4 acc[8];
#pragma unroll
  for (int nt = 0; nt < 8; nt++) acc[nt] = (f32x4){0.f, 0.f, 0.f, 0.f};

#pragma unroll
  for (int kc = 0; kc < 4; kc++) {
#pragma unroll
    for (int nt = 0; nt < 8; nt++) {
      bf16x8 wf = *(const bf16x8*)&WL[(nt * 4 + kc) * 64 + lane];
      acc[nt] = __builtin_amdgcn_mfma_f32_16x16x32_bf16(wf, xb[kc], acc[nt], 0, 0, 0);
    }
  }

  __syncthreads();   // all waves done reading WL
  uint32* Ys = (uint32*)WL;   // [64][36], stride 144B
#pragma unroll
  for (int nt = 0; nt < 8; nt++)
    Ys[(wave * 16 + m) * 36 + nt * 4 + quad] =
        pack_fp8x4(acc[nt][0], acc[nt][1], acc[nt][2], acc[nt][3]);
  __syncthreads();

#pragma unroll
  for (int it = 0; it < 2; it++) {
    int f = tid + 256 * it;        // 0..511
    int row = f >> 3;
    int cu = (f & 7) * 4;
    int grow = row0 + row;
    if (grow < M) *(uint4*)(P + (size_t)grow * 32 + cu) = *(const uint4*)(&Ys[row * 36 + cu]);
  }
}

// ---------------------------------------------------------------------------
// Fused attention + aggregation, WAVE-PER-DST, TWO-PHASE, fp8 tables.
// Segment src_idx/ew prefetched into LDS (coalesced, wave-synchronous);
// phase 1 x4 unrolled -> 4 p_src row-gathers in flight.
// Phase 2 (agg): 32 lanes per fp8 row, 8 gathers in flight per lane.
// (R7 structure — verified best at 158.5 us.)
// ---------------------------------------------------------------------------
__global__ __launch_bounds__(256) void attn_agg_kernel(
    const uint32* __restrict__ p_src_f8, const uint32* __restrict__ p_dst_f8,
    const float* __restrict__ w2, const float* __restrict__ ew,
    const int* __restrict__ src_idx, const int* __restrict__ off,
    const uint32* __restrict__ h_src_f8,
    float* __restrict__ attn_out, uint32* __restrict__ h_glob_bf, int N_dst) {
  const int tid = threadIdx.x;
  const int wv = tid >> 6;
  const int lane = tid & 63;
  const int v = blockIdx.x * 4 + wv;

  __shared__ float sex[4][SCAPW];
  __shared__ int ssrc[4][SCAPW];
  __shared__ float sew[4][SCAPW];
  if (v >= N_dst) return;

  const int lo = off[v], hi = off[v + 1];
  const int deg = hi - lo;
  const int sub = lane & 15;   // lane covers channels sub*8..+7 (score)
  const int eg = lane >> 4;    // edge slot 0..3 (score)
  const bool fast = (deg <= SCAPW);

  // per-lane w2 segment + decoded p_dst segment (row wave-uniform, L1-hot)
  float4 wA = *(const float4*)(w2 + sub * 8);
  float4 wB = *(const float4*)(w2 + sub * 8 + 4);
  uint2 pdu = *(const uint2*)(p_dst_f8 + (size_t)v * 32 + sub * 2);
  f32x2 pd0 = __builtin_amdgcn_cvt_pk_f32_fp8(pdu.x, false);
  f32x2 pd1 = __builtin_amdgcn_cvt_pk_f32_fp8(pdu.x, true);
  f32x2 pd2 = __builtin_amdgcn_cvt_pk_f32_fp8(pdu.y, false);
  f32x2 pd3 = __builtin_amdgcn_cvt_pk_f32_fp8(pdu.y, true);

  float den = 0.f;

  if (fast) {
    // prefetch segment indices + weights (coalesced; wave-synchronous,
    // producer == consumer wave, no barrier needed)
    for (int i = lane; i < deg; i += 64) {
      ssrc[wv][i] = src_idx[lo + i];
      sew[wv][i] = ew[lo + i];
    }
    // ---- phase 1: scores, x4 unrolled (4 row-gathers in flight) ----
    for (int base = 0; base < deg; base += 16) {
      int ei[4], ss[4];
      float ewv[4];
      uint2 us[4];
      bool vl[4];
#pragma unroll
      for (int j = 0; j < 4; j++) {
        ei[j] = base + j * 4 + eg;
        vl[j] = ei[j] < deg;
        const int ii = vl[j] ? ei[j] : 0;
        ss[j] = ssrc[wv][ii];
        ewv[j] = sew[wv][ii];
        us[j] = *(const uint2*)(p_src_f8 + (size_t)ss[j] * 32 + sub * 2);
      }
#pragma unroll
      for (int j = 0; j < 4; j++) {
        if (!vl[j]) continue;
        float sc = score8(us[j], pd0, pd1, pd2, pd3, wA, wB);
#pragma unroll
        for (int o = 1; o <= 8; o <<= 1) sc += __shfl_xor(sc, o, 64);
        float e = __expf(sc * ewv[j]);
        if (sub == 0) sex[wv][ei[j]] = e;
        den += (sub == 0) ? e : 0.f;
      }
    }
  } else {
    // ---- slow path (deg > SCAPW): original global-staged loop ----
    for (int base = 0; base < deg; base += 8) {
      const int ei0 = base + eg;
      const int ei1 = base + 4 + eg;
      const bool v0 = ei0 < deg;
      const bool v1 = ei1 < deg;
      int s0 = 0, s1 = 0;
      float ew0 = 0.f, ew1 = 0.f;
      uint2 us0, us1;
      us0.x = us0.y = us1.x = us1.y = 0u;
      if (v0) {
        const int e = lo + ei0;
        s0 = src_idx[e];
        ew0 = ew[e];
        us0 = *(const uint2*)(p_src_f8 + (size_t)s0 * 32 + sub * 2);
      }
      if (v1) {
        const int e = lo + ei1;
        s1 = src_idx[e];
        ew1 = ew[e];
        us1 = *(const uint2*)(p_src_f8 + (size_t)s1 * 32 + sub * 2);
      }
      float ex0 = 0.f, ex1 = 0.f;
      if (v0) {
        float sc = score8(us0, pd0, pd1, pd2, pd3, wA, wB);
#pragma unroll
        for (int o = 1; o <= 8; o <<= 1) sc += __shfl_xor(sc, o, 64);
        ex0 = __expf(sc * ew0);
        if (sub == 0) attn_out[lo + ei0] = ex0;
      }
      if (v1) {
        float sc = score8(us1, pd0, pd1, pd2, pd3, wA, wB);
#pragma unroll
        for (int o = 1; o <= 8; o <<= 1) sc += __shfl_xor(sc, o, 64);
        ex1 = __expf(sc * ew1);
        if (sub == 0) attn_out[lo + ei1] = ex1;
      }
      den += (sub == 0) ? (ex0 + ex1) : 0.f;
    }
  }
#pragma unroll
  for (int o = 1; o <= 32; o <<= 1) den += __shfl_xor(den, o, 64);
  const float inv = (deg > 0) ? 1.0f / den : 0.0f;

  // ---- phase 2: aggregation (32 lanes per fp8 row, 2 edges per step) ----
  const int c4 = lane & 31;    // channel group: channels c4*4..+3
  const int hw = lane >> 5;    // which edge of the pair
  float a0 = 0.f, a1 = 0.f, a2 = 0.f, a3 = 0.f;

  if (fast) {
    const int pad = (deg + 15) & ~15;
    for (int i = deg + lane; i < pad; i += 64) { sex[wv][i] = 0.f; ssrc[wv][i] = 0; }
    for (int i = lane; i < deg; i += 64) attn_out[lo + i] = sex[wv][i] * inv;
    for (int b = 0; b < pad; b += 16) {
#pragma unroll
      for (int j = 0; j < 8; j++) {
        const int idx = b + j * 2 + hw;
        float ex = sex[wv][idx];
        int s = ssrc[wv][idx];
        uint32 u = h_src_f8[(size_t)s * 32 + c4];
        f32x2 h0 = __builtin_amdgcn_cvt_pk_f32_fp8(u, false);
        f32x2 h1 = __builtin_amdgcn_cvt_pk_f32_fp8(u, true);
        a0 = fmaf(ex, h0.x, a0);
        a1 = fmaf(ex, h0.y, a1);
        a2 = fmaf(ex, h1.x, a2);
        a3 = fmaf(ex, h1.y, a3);
      }
    }
  } else {
    for (int b = 0; b < deg; b += 16) {
#pragma unroll
      for (int j = 0; j < 8; j++) {
        const int idx = b + j * 2 + hw;
        float ex = 0.f;
        int s = 0;
        if (idx < deg) { ex = attn_out[lo + idx]; s = src_idx[lo + idx]; }
        uint32 u = h_src_f8[(size_t)s * 32 + c4];
        f32x2 h0 = __builtin_amdgcn_cvt_pk_f32_fp8(u, false);
        f32x2 h1 = __builtin_amdgcn_cvt_pk_f32_fp8(u, true);
        a0 = fmaf(ex, h0.x, a0);
        a1 = fmaf(ex, h0.y, a1);
        a2 = fmaf(ex, h1.x, a2);
        a3 = fmaf(ex, h1.y, a3);
      }
    }
    // normalize attn AFTER all reads (same wave, sequential)
    for (int i = lane; i < deg; i += 64) attn_out[lo + i] *= inv;
  }

  // reduce the 2 edge-halves (lanes differ in bit 5)
  a0 += __shfl_xor(a0, 32, 64);
  a1 += __shfl_xor(a1, 32, 64);
  a2 += __shfl_xor(a2, 32, 64);
  a3 += __shfl_xor(a3, 32, 64);
  if (hw == 0) {   // lanes 0..31 hold channels c4*4..+3
    uint2 o;
    o.x = pack_bf2(a0 * inv, a1 * inv);
    o.y = pack_bf2(a2 * inv, a3 * inv);
    *(uint2*)(h_glob_bf + (size_t)v * 64 + c4 * 2) = o;
  }
}

// ---------------------------------------------------------------------------
// MFMA output projection + fused LayerNorm. 128 thr / 32 rows per block
// (313 blocks -> ~1.2 blocks/CU; 256-thr/64-row variant starved 99 CUs and
// regressed — keep many small blocks for this fixed-work kernel).
// FULL Wo_frag (64KB) staged into LDS via DMA (zero VGPR cost).
// ---------------------------------------------------------------------------
__global__ __launch_bounds__(128) void out_mfma_ln(
    const float* __restrict__ h_dst, const ushort_t* __restrict__ h_glob_bf,
    const ushort_t* __restrict__ Wo_frag,
    const float* __restrict__ bo,
    const float* __restrict__ gamma, const float* __restrict__ beta,
    float* __restrict__ y, int N) {
  __shared__ uint4 WL[4096];   // 64KB: all Wo fragments
  const int tid = threadIdx.x;
  const int w = tid >> 6;
  const int lane = tid & 63;
  const int m = lane & 15;
  const int quad = lane >> 4;
  const int row0 = blockIdx.x * 32 + w * 16;
  const int ra = min(row0 + m, N - 1);
  const uint4* Wg = (const uint4*)Wo_frag;

  // stage all 4096 granules: thread t covers t+128j (lane*16 implicit)
#pragma unroll
  for (int j = 0; j < 32; j++)
    gload_lds16(Wg + tid + 128 * j, &WL[(tid & ~63) + 128 * j]);

  // hoist all A-fragment loads (8 fp32 dwordx4 + 4 bf16 dwordx4, independent)
  float4 f0[4], f1[4];
  bf16x8 ag[4];
#pragma unroll
  for (int kc = 0; kc < 4; kc++) {
    const float* p = h_dst + (size_t)ra * D128 + kc * 32 + quad * 8;
    f0[kc] = *(const float4*)p;
    f1[kc] = *(const float4*)(p + 4);
  }
#pragma unroll
  for (int kc = 0; kc < 4; kc++)
    ag[kc] = *(const bf16x8*)(h_glob_bf + (size_t)ra * D128 + kc * 32 + quad * 8);

  // bias/gamma/beta registers for channels nt*16+m (L2-hot, reused 4x)
  float bo_r[8], gm_r[8], bt_r[8];
#pragma unroll
  for (int nt = 0; nt < 8; nt++) {
    bo_r[nt] = bo[nt * 16 + m];
    gm_r[nt] = gamma[nt * 16 + m];
    bt_r[nt] = beta[nt * 16 + m];
  }

  __syncthreads();   // drains vmcnt -> WL complete

  f32x4 acc[8];
#pragma unroll
  for (int nt = 0; nt < 8; nt++) acc[nt] = (f32x4){0.f, 0.f, 0.f, 0.f};

#pragma unroll
  for (int kc = 0; kc < 8; kc++) {
    bf16x8 a = (kc < 4) ? bf16x8_of(f0[kc & 3], f1[kc & 3]) : ag[kc & 3];
#pragma unroll
    for (int nt = 0; nt < 8; nt++) {
      bf16x8 bfr = *(const bf16x8*)&WL[(nt * 8 + kc) * 64 + lane];
      acc[nt] = __builtin_amdgcn_mfma_f32_16x16x32_bf16(a, bfr, acc[nt], 0, 0, 0);
    }
  }

#pragma unroll
  for (int r = 0; r < 4; r++) {
    const int grow = row0 + quad * 4 + r;
    const int gr = min(grow, N - 1);
    float x[8];
    float s1 = 0.f, s2 = 0.f;
#pragma unroll
    for (int nt = 0; nt < 8; nt++) {
      float hd = h_dst[(size_t)gr * D128 + nt * 16 + m];
      float xv = hd + acc[nt][r] + bo_r[nt];
      x[nt] = xv;
      s1 += xv;
      s2 = fmaf(xv, xv, s2);
    }
#pragma unroll
    for (int o = 1; o <= 8; o <<= 1) {
      s1 += __shfl_xor(s1, o, 64);
      s2 += __shfl_xor(s2, o, 64);
    }
    float mu = s1 * (1.0f / 128.0f);
    float var = s2 * (1.0f / 128.0f) - mu * mu;
    float rstd = __builtin_amdgcn_rcpf(sqrtf(var + 1e-5f));
    if (grow < N) {
#pragma unroll
      for (int nt = 0; nt < 8; nt++) {
        y[(size_t)grow * D128 + nt * 16 + m] = (x[nt] - mu) * rstd * gm_r[nt] + bt_r[nt];
      }
    }
  }
}

extern "C" void kernel_launch(void* const* d_in, const int* in_sizes, int n_in,
                              void* d_out, int out_size, void* d_ws, size_t ws_size,
                              hipStream_t stream) {
  const float* h_src = (const float*)d_in[0];
  const float* h_dst = (const float*)d_in[1];
  const float* s_emb = (const float*)d_in[2];
  const float* ew    = (const float*)d_in[3];
  const int* src_idx = (const int*)d_in[4];
  const int* dst_idx = (const int*)d_in[5];
  const float* W1    = (const float*)d_in[6];
  const float* w2    = (const float*)d_in[7];
  const float* Wo    = (const float*)d_in[8];
  const float* bo    = (const float*)d_in[9];
  const float* gamma = (const float*)d_in[10];
  const float* beta  = (const float*)d_in[11];

  const int N_src = in_sizes[0] / D128;
  const int N_dst = in_sizes[1] / D128;
  const int E = in_sizes[3];

  float* out_y = (float*)d_out;                       // [N_dst*128]
  float* out_attn = out_y + (size_t)N_dst * D128;     // [E]

  // ws layout:
  uint32* p_src_f8 = (uint32*)d_ws;                            // N_src*32 (fp8 rows)
  uint32* p_dst_f8 = p_src_f8 + (size_t)N_src * 32;            // N_dst*32
  uint32* h_src_f8 = p_dst_f8 + (size_t)N_dst * 32;            // N_src*32
  uint32* h_glob_bf = h_src_f8 + (size_t)N_src * 32;           // N_dst*64 (bf16)
  int* seg_off = (int*)(h_glob_bf + (size_t)N_dst * 64);       // N_dst+1
  ushort_t* Wfrag = (ushort_t*)(seg_off + N_dst + 1 + 3);      // 32768 shorts
  ushort_t* Wo_frag = Wfrag + 32768;                           // 32768 shorts

  const int nblk_a = (N_src + 63) / 64;
  const int nblk_b = (N_dst + 63) / 64;
  const int nb_seg = (E + 255) / 256;

  prep_all<<<32 + nb_seg, 256, 0, stream>>>(
      W1, Wo, dst_idx, Wfrag, Wo_frag, seg_off, E, N_dst);
  gemm_mfma<<<nblk_a + nblk_b, 256, 0, stream>>>(
      h_src, s_emb, Wfrag, p_src_f8, p_dst_f8, h_src_f8, N_src, N_dst, nblk_a);
  attn_agg_kernel<<<(N_dst + 3) / 4, 256, 0, stream>>>(
      p_src_f8, p_dst_f8, w2, ew, src_idx, seg_off, h_src_f8, out_attn,
      h_glob_bf, N_dst);
  out_mfma_ln<<<(N_dst + 31) / 32, 128, 0, stream>>>(
      h_dst, (const ushort_t*)h_glob_bf, Wo_frag,
      bo, gamma, beta, out_y, N_dst);
}